// Round 15
// baseline (3768.698 us; speedup 1.0000x reference)
//
#include <hip/hip_runtime.h>
#include <cstdint>

typedef __attribute__((ext_vector_type(8))) short bf16x8;
typedef __attribute__((ext_vector_type(4))) float f32x4;
typedef __attribute__((ext_vector_type(4))) unsigned int u32x4;

#define AS1 __attribute__((address_space(1)))
#define AS3 __attribute__((address_space(3)))

__device__ __forceinline__ unsigned short f2bf(float f) {
  unsigned int u = __builtin_bit_cast(unsigned int, f);
  return (unsigned short)((u + 0x7fffu + ((u >> 16) & 1u)) >> 16);
}
__device__ __forceinline__ float bf2f(unsigned short h) {
  unsigned int u = ((unsigned int)h) << 16;
  return __builtin_bit_cast(float, u);
}
__device__ __forceinline__ float sigm(float x) { return 1.f / (1.f + __expf(-x)); }
__device__ __forceinline__ float tanh_f(float x) {
  float e = __expf(2.f * x);          // inf-safe
  return 1.f - 2.f / (e + 1.f);
}
__device__ __forceinline__ void gload16(const void* g, void* l) {
  __builtin_amdgcn_global_load_lds((const AS1 unsigned int*)g, (AS3 unsigned int*)l, 16, 0, 0);
}
// XOR-swizzle for [rows][64]-bf16 tiles (8 slots of 16B per 128B row):
// pre-swizzled GLOBAL source + swizzled read, linear LDS dest (rule #21).
__device__ __forceinline__ int swz(int e) { return e ^ (((e >> 6) & 7) << 3); }

// ---------------- setup / conversion kernels ----------------

__global__ __launch_bounds__(256) void conv_wh_kernel(
    const float4* __restrict__ w0, const float4* __restrict__ w1,
    const float4* __restrict__ w2, const float4* __restrict__ w3,
    unsigned long long* __restrict__ dst) {
  int i = blockIdx.x * 256 + threadIdx.x;           // 0 .. 1M-1 (float4 units)
  int g = i >> 18;
  const float4* s = g == 0 ? w0 : g == 1 ? w1 : g == 2 ? w2 : w3;
  float4 v = s[i & 0x3FFFF];
  unsigned long long p = (unsigned long long)f2bf(v.x) |
                         ((unsigned long long)f2bf(v.y) << 16) |
                         ((unsigned long long)f2bf(v.z) << 32) |
                         ((unsigned long long)f2bf(v.w) << 48);
  dst[i] = p;
}

__global__ __launch_bounds__(256) void conv_wiT_kernel(
    const float* __restrict__ w0, const float* __restrict__ w1,
    const float* __restrict__ w2, const float* __restrict__ w3,
    unsigned short* __restrict__ dst) {
  __shared__ unsigned short ls[64][72];
  int bid = blockIdx.x;                 // 0..1023 : 4 gates x 16x16 tiles
  int g = bid >> 8;
  int t2 = bid & 255;
  int tj = t2 & 15, tk = t2 >> 4;
  const float* W = g == 0 ? w0 : g == 1 ? w1 : g == 2 ? w2 : w3;
  int k0 = tk * 64, j0 = tj * 64;
  int ty = threadIdx.x >> 6, tx = threadIdx.x & 63;
#pragma unroll
  for (int r = 0; r < 16; ++r) {
    int k = k0 + ty * 16 + r;
    ls[tx][ty * 16 + r] = f2bf(W[k * 1024 + j0 + tx]);
  }
  __syncthreads();
#pragma unroll
  for (int r = 0; r < 16; ++r) {
    int jl = ty * 16 + r;
    dst[(size_t)(g * 1024 + j0 + jl) * 1024 + k0 + tx] = ls[jl][tx];
  }
}

__global__ __launch_bounds__(256) void conv_bias_kernel(
    const float* __restrict__ b0, const float* __restrict__ b1,
    const float* __restrict__ b2, const float* __restrict__ b3,
    float* __restrict__ dst) {
  int i = blockIdx.x * 256 + threadIdx.x;  // 0..4095
  const float* s = (i >> 10) == 0 ? b0 : (i >> 10) == 1 ? b1 : (i >> 10) == 2 ? b2 : b3;
  dst[i] = s[i & 1023];
}

__global__ __launch_bounds__(256) void conv_x_kernel(
    const float4* __restrict__ src, unsigned long long* __restrict__ dst, int n4) {
  int i = blockIdx.x * 256 + threadIdx.x;
  if (i < n4) {
    float4 v = src[i];
    dst[i] = (unsigned long long)f2bf(v.x) |
             ((unsigned long long)f2bf(v.y) << 16) |
             ((unsigned long long)f2bf(v.z) << 32) |
             ((unsigned long long)f2bf(v.w) << 48);
  }
}

// ---------------- fused step + next-chunk xproj slice ----------------
// One launch = 512 step blocks (bx < nStep) + 256 xproj-slice blocks.
// Unified LDS 48KB -> 3 blocks/CU -> ALL 768 blocks co-resident: xproj
// waves (prio 0) fill the latency-bound step waves' (MFMA prio 1) stall
// slots (m114 co-schedule / T5 role split). Step path: (32b x 64j x 4g)
// tile, 4 waves, 2-BUFFER single-barrier pipeline (1-deep prefetch),
// XCD map bb in {4x..4x+3}. xproj path: r6-proven 128x128 tile, BK=64,
// 2-sync loop, swizzled staging/reads, lsC bounce + nt stores — computes
// tile (xTileBase + bx - nStep) of the NEXT chunk's Xp.
__global__ __launch_bounds__(256, 3) void fused_step_kernel(
    const unsigned short* __restrict__ Wh,   // [4096][1024]
    const unsigned short* __restrict__ hT,   // [1024][1024]
    const unsigned short* __restrict__ Xp,   // this step's x-proj [1024][4096]
    const float* __restrict__ bias,          // [4096]
    float* __restrict__ cst,                 // fp32 cell state
    float* __restrict__ out_h, float* __restrict__ out_ht,
    float* __restrict__ out_ct,
    unsigned short* __restrict__ hT_next,
    int isLast, int nStep,
    const unsigned short* __restrict__ Axp,  // next-chunk Xbf [Mc][1024]
    const unsigned short* __restrict__ Bt,   // WiT [4096][1024]
    unsigned short* __restrict__ Cxp,        // next-chunk Xp [Mc][4096]
    int xTileBase) {
  __shared__ __align__(16) char smem[49152];   // 48KB union
  int tid = threadIdx.x, w = tid >> 6, lane = tid & 63;
  int l15 = lane & 15, l4 = lane >> 4;
  int bx = blockIdx.x;

  if (bx < nStep) {
    // ================= LSTM step path =================
    unsigned short* lsA0 = (unsigned short*)smem;           // [2][128*64]
    unsigned short* lsB0 = lsA0 + 16384;                    // [2][64*64]
    int xcd = bx & 7, idx = bx >> 3;
    int bb = xcd * 4 + (idx & 3);
    int bj = idx >> 2;
    int b0 = bb * 32, j0 = bj * 64;
    int wm = w >> 1, wn = w & 1;
    int bbase = b0 + wm * 16 + l4 * 4;

    // prefetch epilogue operands (oldest in vmcnt FIFO)
    float bias_pre[4][2];
    float c_pre[2][4];
    unsigned short xp_pre[4][2][4];
#pragma unroll
    for (int n = 0; n < 2; ++n) {
      int j = j0 + wn * 32 + n * 16 + l15;
#pragma unroll
      for (int g = 0; g < 4; ++g) bias_pre[g][n] = bias[g * 1024 + j];
#pragma unroll
      for (int r = 0; r < 4; ++r) {
        c_pre[n][r] = cst[(size_t)(bbase + r) * 1024 + j];
#pragma unroll
        for (int g = 0; g < 4; ++g)
          xp_pre[g][n][r] = Xp[(size_t)(bbase + r) * 4096 + g * 1024 + j];
      }
    }

    f32x4 acc[4][2];
#pragma unroll
    for (int g = 0; g < 4; ++g)
#pragma unroll
      for (int n = 0; n < 2; ++n) acc[g][n] = (f32x4)0.f;

    auto stage = [&](int buf, int kk) {        // 6 gload16 per thread
      unsigned short* dA = lsA0 + buf * 8192;
      unsigned short* dB = lsB0 + buf * 4096;
#pragma unroll
      for (int ld = 0; ld < 4; ++ld) {
        int cid = ld * 256 + tid;
        int r = cid >> 3, kc = (cid & 7) * 8;  // r: 0..127
        int sk = kk + (kc ^ ((r & 7) << 3));
        int grow = ((r >> 4) & 3) * 1024 + b0 + (r >> 6) * 16 + (r & 15);
        gload16(&Wh[(size_t)grow * 1024 + sk], &dA[(ld * 256 + w * 64) * 8]);
      }
#pragma unroll
      for (int u = 0; u < 2; ++u) {
        int cid = u * 256 + tid;
        int r = cid >> 3, kc = (cid & 7) * 8;  // r: 0..63
        int sk = kk + (kc ^ ((r & 7) << 3));
        gload16(&hT[(size_t)(j0 + r) * 1024 + sk], &dB[(u * 256 + w * 64) * 8]);
      }
    };
    auto compute = [&](int buf) {
      unsigned short* sA = lsA0 + buf * 8192;
      unsigned short* sB = lsB0 + buf * 4096;
      bf16x8 af[4][2], bfr[2][2];
#pragma unroll
      for (int g = 0; g < 4; ++g)
#pragma unroll
        for (int kss = 0; kss < 2; ++kss) {
          int e = (wm * 64 + g * 16 + l15) * 64 + kss * 32 + l4 * 8;
          af[g][kss] = *(const bf16x8*)&sA[swz(e)];
        }
#pragma unroll
      for (int n = 0; n < 2; ++n)
#pragma unroll
        for (int kss = 0; kss < 2; ++kss) {
          int e = (wn * 32 + n * 16 + l15) * 64 + kss * 32 + l4 * 8;
          bfr[n][kss] = *(const bf16x8*)&sB[swz(e)];
        }
      __builtin_amdgcn_s_setprio(1);
#pragma unroll
      for (int g = 0; g < 4; ++g)
#pragma unroll
        for (int n = 0; n < 2; ++n)
#pragma unroll
          for (int kss = 0; kss < 2; ++kss)
            acc[g][n] = __builtin_amdgcn_mfma_f32_16x16x32_bf16(
                af[g][kss], bfr[n][kss], acc[g][n], 0, 0, 0);
      __builtin_amdgcn_s_setprio(0);
    };

    // 2-buffer single-barrier pipeline, 1-deep prefetch.
    // iter it: {vmcnt(0): my stage(it) landed; BAR (also certifies everyone's
    // compute(it-1) reads via their lgkm-before-bar); stage(it+1)->buf^1
    // (safe: last read at it-1); compute(it); lgkm(0)}.
    stage(0, 0);
#pragma unroll
    for (int it = 0; it < 16; ++it) {
      asm volatile("s_waitcnt vmcnt(0)" ::: "memory");
      __builtin_amdgcn_sched_barrier(0);
      __builtin_amdgcn_s_barrier();
      __builtin_amdgcn_sched_barrier(0);
      if (it + 1 < 16) stage((it + 1) & 1, (it + 1) * 64);
      compute(it & 1);
      asm volatile("s_waitcnt lgkmcnt(0)" ::: "memory");
      __builtin_amdgcn_sched_barrier(0);
    }

    // epilogue
#pragma unroll
    for (int n = 0; n < 2; ++n) {
      int j = j0 + wn * 32 + n * 16 + l15;
      float hn[4], cn[4];
#pragma unroll
      for (int r = 0; r < 4; ++r) {
        int b = bbase + r;
        float pi = acc[0][n][r] + bf2f(xp_pre[0][n][r]) + bias_pre[0][n];
        float pf = acc[1][n][r] + bf2f(xp_pre[1][n][r]) + bias_pre[1][n];
        float pg = acc[2][n][r] + bf2f(xp_pre[2][n][r]) + bias_pre[2][n];
        float po = acc[3][n][r] + bf2f(xp_pre[3][n][r]) + bias_pre[3][n];
        float ig = sigm(pi), fg = sigm(pf), gg = tanh_f(pg), og = sigm(po);
        float c_new = fg * c_pre[n][r] + ig * gg;
        cst[(size_t)b * 1024 + j] = c_new;
        cn[r] = c_new;
        hn[r] = og * tanh_f(c_new);
        __builtin_nontemporal_store(hn[r], &out_h[(size_t)b * 1024 + j]);
      }
      unsigned long long hp = (unsigned long long)f2bf(hn[0]) |
                              ((unsigned long long)f2bf(hn[1]) << 16) |
                              ((unsigned long long)f2bf(hn[2]) << 32) |
                              ((unsigned long long)f2bf(hn[3]) << 48);
      *(unsigned long long*)&hT_next[(size_t)j * 1024 + bbase] = hp;
      if (isLast) {
#pragma unroll
        for (int r = 0; r < 4; ++r) {
          int b = bbase + r;
          __builtin_nontemporal_store(hn[r], &out_ht[(size_t)b * 1024 + j]);
          __builtin_nontemporal_store(cn[r], &out_ct[(size_t)b * 1024 + j]);
        }
      }
    }
  } else {
    // ================= xproj 128x128 slice path (r6-proven) =================
    unsigned short* lsA = (unsigned short*)smem;       // [128*64] 16KB
    unsigned short* lsB = lsA + 8192;                  // [128*64] 16KB
    int g = xTileBase + (bx - nStep);
    int bm = g >> 5, bn = g & 31;
    int m0 = bm * 128, n0 = bn * 128;
    int wm = w >> 1, wn = w & 1;

    f32x4 acc[4][4];
#pragma unroll
    for (int i = 0; i < 4; ++i)
#pragma unroll
      for (int j = 0; j < 4; ++j) acc[i][j] = (f32x4)0.f;

    for (int ks = 0; ks < 16; ++ks) {
      int kk = ks * 64;
      __syncthreads();   // everyone done reading previous tile
#pragma unroll
      for (int ld = 0; ld < 4; ++ld) {
        int cid = ld * 256 + tid;
        int r = cid >> 3, kc = (cid & 7) * 8;
        int sk = kk + (kc ^ ((r & 7) << 3));
        gload16(&Axp[(size_t)(m0 + r) * 1024 + sk], &lsA[(ld * 256 + w * 64) * 8]);
        gload16(&Bt[(size_t)(n0 + r) * 1024 + sk], &lsB[(ld * 256 + w * 64) * 8]);
      }
      __syncthreads();   // data ready (drains vmcnt)
      bf16x8 af[4][2], bfr[4][2];
#pragma unroll
      for (int cm = 0; cm < 4; ++cm)
#pragma unroll
        for (int kss = 0; kss < 2; ++kss) {
          int e = (wm * 64 + cm * 16 + l15) * 64 + kss * 32 + l4 * 8;
          af[cm][kss] = *(const bf16x8*)&lsA[swz(e)];
        }
#pragma unroll
      for (int cn = 0; cn < 4; ++cn)
#pragma unroll
        for (int kss = 0; kss < 2; ++kss) {
          int e = (wn * 64 + cn * 16 + l15) * 64 + kss * 32 + l4 * 8;
          bfr[cn][kss] = *(const bf16x8*)&lsB[swz(e)];
        }
      // prio 0: step waves' MFMA keeps priority
#pragma unroll
      for (int cm = 0; cm < 4; ++cm)
#pragma unroll
        for (int cn = 0; cn < 4; ++cn)
#pragma unroll
          for (int kss = 0; kss < 2; ++kss)
            acc[cm][cn] = __builtin_amdgcn_mfma_f32_16x16x32_bf16(
                af[cm][kss], bfr[cn][kss], acc[cm][cn], 0, 0, 0);
    }

    // epilogue: acc -> LDS bounce -> nt 16B stores
    __syncthreads();
    unsigned short* lsC = (unsigned short*)smem;   // [128][136] = 34816B
#pragma unroll
    for (int cm = 0; cm < 4; ++cm)
#pragma unroll
      for (int cn = 0; cn < 4; ++cn)
#pragma unroll
        for (int r = 0; r < 4; ++r) {
          int row = wm * 64 + cm * 16 + l4 * 4 + r;
          int col = wn * 64 + cn * 16 + l15;
          lsC[row * 136 + col] = f2bf(acc[cm][cn][r]);
        }
    __syncthreads();
#pragma unroll
    for (int u = 0; u < 8; ++u) {
      int chunk = u * 256 + tid;        // 128 rows x 16 chunks of 16B
      int row = chunk >> 4, c8 = chunk & 15;
      u32x4 v = *(const u32x4*)&lsC[row * 136 + c8 * 8];
      __builtin_nontemporal_store(
          v, (u32x4*)&Cxp[(size_t)(m0 + row) * 4096 + n0 + c8 * 8]);
    }
  }
}

// ---------------- host ----------------
extern "C" void kernel_launch(void* const* d_in, const int* in_sizes, int n_in,
                              void* d_out, int out_size, void* d_ws, size_t ws_size,
                              hipStream_t stream) {
  const float* X   = (const float*)d_in[0];
  const float* Wii = (const float*)d_in[1];
  const float* Whi = (const float*)d_in[2];
  const float* bi  = (const float*)d_in[3];
  const float* Wif = (const float*)d_in[4];
  const float* Whf = (const float*)d_in[5];
  const float* bfv = (const float*)d_in[6];
  const float* Wig = (const float*)d_in[7];
  const float* Whg = (const float*)d_in[8];
  const float* bg  = (const float*)d_in[9];
  const float* Wio = (const float*)d_in[10];
  const float* Who = (const float*)d_in[11];
  const float* bo  = (const float*)d_in[12];
  float* out = (float*)d_out;

  char* wsp = (char*)d_ws;
  size_t off = 0;
  auto walloc = [&](size_t b) -> void* {
    void* p = wsp + off;
    off += (b + 255) & ~(size_t)255;
    return p;
  };
  unsigned short* WiT = (unsigned short*)walloc(4096ull * 1024 * 2);
  unsigned short* Wh  = (unsigned short*)walloc(4096ull * 1024 * 2);
  float* bias = (float*)walloc(4096 * 4);
  unsigned short* hT0 = (unsigned short*)walloc(1024ull * 1024 * 2);
  unsigned short* hT1 = (unsigned short*)walloc(1024ull * 1024 * 2);
  float* cbuf = (float*)walloc(1024ull * 1024 * 4);
  size_t fixed = off;

  long long avail = (long long)ws_size - (long long)fixed - (1ll << 20);
  int Tc = 16;                          // chunks of Tc steps, Xbf/Xp dbuf'd
  while (Tc > 1 && (long long)Tc * 2 * (10ll << 20) > avail) Tc >>= 1;
  int nc = 128 / Tc;
  unsigned short* Xbf[2], *Xp[2];
  Xbf[0] = (unsigned short*)walloc((size_t)Tc * 1024 * 1024 * 2);
  Xbf[1] = (unsigned short*)walloc((size_t)Tc * 1024 * 1024 * 2);
  Xp[0]  = (unsigned short*)walloc((size_t)Tc * 1024 * 4096 * 2);
  Xp[1]  = (unsigned short*)walloc((size_t)Tc * 1024 * 4096 * 2);

  conv_wh_kernel<<<4096, 256, 0, stream>>>((const float4*)Whi, (const float4*)Whf,
                                           (const float4*)Whg, (const float4*)Who,
                                           (unsigned long long*)Wh);
  conv_wiT_kernel<<<1024, 256, 0, stream>>>(Wii, Wif, Wig, Wio, WiT);
  conv_bias_kernel<<<16, 256, 0, stream>>>(bi, bfv, bg, bo, bias);
  hipMemsetAsync(hT0, 0, 1024ull * 1024 * 2, stream);
  hipMemsetAsync(cbuf, 0, 1024ull * 1024 * 4, stream);

  // prologue: chunk 0 conv + full xproj (all blocks take the xproj path)
  conv_x_kernel<<<Tc * 1024, 256, 0, stream>>>(
      (const float4*)X, (unsigned long long*)Xbf[0], Tc * 262144);
  fused_step_kernel<<<Tc * 256, 256, 0, stream>>>(
      Wh, hT0, Xp[0], bias, cbuf, out, out, out, hT1, 0,
      0 /*nStep*/, Xbf[0], WiT, Xp[0], 0);

  for (int i = 0; i < nc; ++i) {
    int cur = i & 1, nxt = cur ^ 1;
    if (i + 1 < nc)  // convert next chunk's X (ready before its slices run)
      conv_x_kernel<<<Tc * 1024, 256, 0, stream>>>(
          (const float4*)(X + (size_t)(i + 1) * Tc * 1048576),
          (unsigned long long*)Xbf[nxt], Tc * 262144);
    for (int s = 0; s < Tc; ++s) {
      int t = i * Tc + s;
      int nX = (i + 1 < nc) ? 256 : 0;  // carry next chunk's xproj slices
      fused_step_kernel<<<512 + nX, 256, 0, stream>>>(
          Wh, (t & 1) ? hT1 : hT0,
          Xp[cur] + (size_t)s * 4194304,
          bias, cbuf,
          out + (size_t)t * 1048576,
          out + 134217728ull,
          out + 135266304ull,
          (t & 1) ? hT0 : hT1,
          (t == 127) ? 1 : 0,
          512 /*nStep*/, Xbf[nxt], WiT, Xp[nxt], s * 256);
    }
  }
}